// Round 1
// baseline (690.671 us; speedup 1.0000x reference)
//
#include <hip/hip_runtime.h>
#include <math.h>

constexpr int NT = 768;      // sequence length N
constexpr int DT = 768;      // model dim D
constexpr int HT = 16;       // heads
constexpr int HDT = 48;      // head dim
constexpr int ZDT = 128;     // pair-rep dim
constexpr int NN = NT * NT;  // 589824
constexpr float LN_EPS = 1e-5f;
constexpr float SCALE = 0.14433756729740643f;  // 48^-0.5

// ---------------------------------------------------------------- LayerNorm(s)
__global__ __launch_bounds__(256) void ln_s_kernel(
    const float* __restrict__ s, const float* __restrict__ w,
    const float* __restrict__ b, float* __restrict__ sn) {
  const int row = blockIdx.x;
  const int t = threadIdx.x;
  const float* x = s + row * DT;
  float v0 = x[t], v1 = x[t + 256], v2 = x[t + 512];
  float sum = v0 + v1 + v2;
  float sq = v0 * v0 + v1 * v1 + v2 * v2;
#pragma unroll
  for (int off = 32; off; off >>= 1) {
    sum += __shfl_xor(sum, off);
    sq += __shfl_xor(sq, off);
  }
  __shared__ float ls[4], lq[4], stats[2];
  const int wid = t >> 6;
  if ((t & 63) == 0) { ls[wid] = sum; lq[wid] = sq; }
  __syncthreads();
  if (t == 0) {
    float S = ls[0] + ls[1] + ls[2] + ls[3];
    float Q = lq[0] + lq[1] + lq[2] + lq[3];
    float mu = S * (1.f / DT);
    float var = Q * (1.f / DT) - mu * mu;
    stats[0] = mu;
    stats[1] = rsqrtf(var + LN_EPS);
  }
  __syncthreads();
  const float mu = stats[0], rs = stats[1];
  float* y = sn + row * DT;
  y[t] = (v0 - mu) * rs * w[t] + b[t];
  y[t + 256] = (v1 - mu) * rs * w[t + 256] + b[t + 256];
  y[t + 512] = (v2 - mu) * rs * w[t + 512] + b[t + 512];
}

// ------------------------------------------- fused q/k/v/g projections (fp32)
// C[64x64] tile per block, 4x4 per thread, KT=32. blockIdx.z picks the matrix.
__global__ __launch_bounds__(256) void proj_kernel(
    const float* __restrict__ sn, const float* __restrict__ qw,
    const float* __restrict__ kw, const float* __restrict__ vw,
    const float* __restrict__ gw, const float* __restrict__ qb,
    float* __restrict__ qo, float* __restrict__ ko, float* __restrict__ vo,
    float* __restrict__ go) {
  __shared__ float As[32][68];  // [k][m] transposed
  __shared__ float Bs[32][68];  // [k][n]
  const int t = threadIdx.x;
  const int m0 = blockIdx.y * 64;
  const int n0 = blockIdx.x * 64;
  const int which = blockIdx.z;
  const float* W = which == 0 ? qw : which == 1 ? kw : which == 2 ? vw : gw;
  float acc[4][4] = {};
  const int r0 = (t >> 4) * 4;
  const int c0 = (t & 15) * 4;
  const int ar = t >> 3;         // 0..31
  const int ak = (t & 7) * 4;    // 0..28
  const int nc = (t & 7) * 8;    // 0..56
  for (int k0 = 0; k0 < DT; k0 += 32) {
    float4 a0 = *(const float4*)&sn[(m0 + ar) * DT + k0 + ak];
    float4 a1 = *(const float4*)&sn[(m0 + ar + 32) * DT + k0 + ak];
    float4 b0 = *(const float4*)&W[(k0 + ar) * DT + n0 + nc];
    float4 b1 = *(const float4*)&W[(k0 + ar) * DT + n0 + nc + 4];
    __syncthreads();
    As[ak + 0][ar] = a0.x; As[ak + 1][ar] = a0.y;
    As[ak + 2][ar] = a0.z; As[ak + 3][ar] = a0.w;
    As[ak + 0][ar + 32] = a1.x; As[ak + 1][ar + 32] = a1.y;
    As[ak + 2][ar + 32] = a1.z; As[ak + 3][ar + 32] = a1.w;
    *(float4*)&Bs[ar][nc] = b0;
    *(float4*)&Bs[ar][nc + 4] = b1;
    __syncthreads();
#pragma unroll
    for (int kk = 0; kk < 32; kk++) {
      float a4[4], b4[4];
      *(float4*)a4 = *(const float4*)&As[kk][r0];
      *(float4*)b4 = *(const float4*)&Bs[kk][c0];
#pragma unroll
      for (int i = 0; i < 4; i++)
#pragma unroll
        for (int j = 0; j < 4; j++) acc[i][j] += a4[i] * b4[j];
    }
  }
  float* out = which == 0 ? qo : which == 1 ? ko : which == 2 ? vo : go;
#pragma unroll
  for (int i = 0; i < 4; i++) {
    float r[4];
#pragma unroll
    for (int j = 0; j < 4; j++) r[j] = acc[i][j];
    if (which == 0) {
#pragma unroll
      for (int j = 0; j < 4; j++) r[j] += qb[n0 + c0 + j];
    } else if (which == 3) {
#pragma unroll
      for (int j = 0; j < 4; j++) r[j] = 1.f / (1.f + __expf(-r[j]));
    }
    *(float4*)&out[(m0 + r0 + i) * DT + n0 + c0] = *(float4*)r;
  }
}

// ---------------------------------- fold z_norm_w into z_w once per call
__global__ __launch_bounds__(256) void zsetup_kernel(
    const float* __restrict__ znw, const float* __restrict__ znb,
    const float* __restrict__ zw, float* __restrict__ w1,
    float* __restrict__ bh) {
  const int t = threadIdx.x;
#pragma unroll
  for (int i = 0; i < 8; i++) {
    int idx = t * 8 + i;
    int c = idx >> 4;
    w1[idx] = znw[c] * zw[idx];
  }
  if (t < HT) {
    float s = 0.f;
    for (int c = 0; c < ZDT; c++) s += znb[c] * zw[c * HT + t];
    bh[t] = s;
  }
}

// ------------------- z LayerNorm + (ZD->H) projection -> att bias [H][N][N]
// roles: slot=t>>5 (row in 8-row batch), hq=(t>>3)&3 (h-quad), cg=t&7 (c-slice)
// W1 slice lives in registers; amortized over 256 rows per block.
__global__ __launch_bounds__(256) void zbias_kernel(
    const float* __restrict__ z, const float* __restrict__ w1,
    const float* __restrict__ bh, float* __restrict__ att) {
  __shared__ float xs[8][128];
  const int t = threadIdx.x;
  const int slot = t >> 5;
  const int hq = (t >> 3) & 3;
  const int cg = t & 7;
  const int c0 = cg * 16;
  const int h0 = hq * 4;
  float4 Wr[16];
#pragma unroll
  for (int j = 0; j < 16; j++)
    Wr[j] = *(const float4*)&w1[(c0 + j) * HT + h0];
  const float4 B4 = *(const float4*)&bh[h0];
  const int row0 = blockIdx.x * 256;
  const int lc = (t & 31) * 4;
  for (int it = 0; it < 32; it++) {
    const int rbase = row0 + it * 8;
    float4 xv = *(const float4*)&z[(rbase + slot) * ZDT + lc];
    __syncthreads();
    *(float4*)&xs[slot][lc] = xv;
    __syncthreads();
    float x[16];
#pragma unroll
    for (int i = 0; i < 4; i++) {
      float4 v = *(const float4*)&xs[slot][c0 + i * 4];
      x[i * 4 + 0] = v.x; x[i * 4 + 1] = v.y;
      x[i * 4 + 2] = v.z; x[i * 4 + 3] = v.w;
    }
    float sum = 0.f, sq = 0.f;
#pragma unroll
    for (int j = 0; j < 16; j++) { sum += x[j]; sq += x[j] * x[j]; }
#pragma unroll
    for (int m = 1; m <= 4; m <<= 1) {
      sum += __shfl_xor(sum, m);
      sq += __shfl_xor(sq, m);
    }
    const float mu = sum * (1.f / 128.f);
    const float rs = rsqrtf(sq * (1.f / 128.f) - mu * mu + LN_EPS);
    float ax = 0.f, ay = 0.f, az = 0.f, aw = 0.f;
#pragma unroll
    for (int j = 0; j < 16; j++) {
      float xc = x[j] - mu;
      ax += xc * Wr[j].x; ay += xc * Wr[j].y;
      az += xc * Wr[j].z; aw += xc * Wr[j].w;
    }
#pragma unroll
    for (int m = 1; m <= 4; m <<= 1) {
      ax += __shfl_xor(ax, m); ay += __shfl_xor(ay, m);
      az += __shfl_xor(az, m); aw += __shfl_xor(aw, m);
    }
    if (cg == 0) {
      const int rid = rbase + slot;
      att[(h0 + 0) * NN + rid] = ax * rs + B4.x;
      att[(h0 + 1) * NN + rid] = ay * rs + B4.y;
      att[(h0 + 2) * NN + rid] = az * rs + B4.z;
      att[(h0 + 3) * NN + rid] = aw * rs + B4.w;
    }
  }
}

// -------------------------- scores: att[h][q][k] = scale*Q.K^T + bias (inplace)
__global__ __launch_bounds__(256) void scores_kernel(
    const float* __restrict__ q, const float* __restrict__ k,
    float* __restrict__ att) {
  __shared__ float Qs[48][68];
  __shared__ float Ks[48][68];
  const int t = threadIdx.x;
  const int m0 = blockIdx.y * 64;
  const int n0 = blockIdx.x * 64;
  const int h = blockIdx.z;
  const int lr = t >> 2;
  const int dq = (t & 3) * 12;
#pragma unroll
  for (int i = 0; i < 3; i++) {
    float4 qv = *(const float4*)&q[(m0 + lr) * DT + h * HDT + dq + i * 4];
    float4 kv = *(const float4*)&k[(n0 + lr) * DT + h * HDT + dq + i * 4];
    Qs[dq + i * 4 + 0][lr] = qv.x; Qs[dq + i * 4 + 1][lr] = qv.y;
    Qs[dq + i * 4 + 2][lr] = qv.z; Qs[dq + i * 4 + 3][lr] = qv.w;
    Ks[dq + i * 4 + 0][lr] = kv.x; Ks[dq + i * 4 + 1][lr] = kv.y;
    Ks[dq + i * 4 + 2][lr] = kv.z; Ks[dq + i * 4 + 3][lr] = kv.w;
  }
  __syncthreads();
  const int r0 = (t >> 4) * 4;
  const int c0 = (t & 15) * 4;
  float acc[4][4] = {};
#pragma unroll
  for (int kk = 0; kk < 48; kk++) {
    float a4[4], b4[4];
    *(float4*)a4 = *(const float4*)&Qs[kk][r0];
    *(float4*)b4 = *(const float4*)&Ks[kk][c0];
#pragma unroll
    for (int i = 0; i < 4; i++)
#pragma unroll
      for (int j = 0; j < 4; j++) acc[i][j] += a4[i] * b4[j];
  }
#pragma unroll
  for (int i = 0; i < 4; i++) {
    float* p = &att[(h * NT + m0 + r0 + i) * NT + n0 + c0];
    float4 bias = *(const float4*)p;
    float4 r;
    r.x = acc[i][0] * SCALE + bias.x;
    r.y = acc[i][1] * SCALE + bias.y;
    r.z = acc[i][2] * SCALE + bias.z;
    r.w = acc[i][3] * SCALE + bias.w;
    *(float4*)p = r;
  }
}

// ------------------------------------------------------- softmax over last dim
__global__ __launch_bounds__(256) void softmax_kernel(float* __restrict__ att) {
  float* p = att + blockIdx.x * NT;
  const int t = threadIdx.x;
  float a = p[t], b = p[t + 256], c = p[t + 512];
  float m = fmaxf(a, fmaxf(b, c));
#pragma unroll
  for (int off = 32; off; off >>= 1) m = fmaxf(m, __shfl_xor(m, off));
  __shared__ float red[4];
  __shared__ float bc[2];
  if ((t & 63) == 0) red[t >> 6] = m;
  __syncthreads();
  if (t == 0) bc[0] = fmaxf(fmaxf(red[0], red[1]), fmaxf(red[2], red[3]));
  __syncthreads();
  const float M = bc[0];
  float e0 = __expf(a - M), e1 = __expf(b - M), e2 = __expf(c - M);
  float s = e0 + e1 + e2;
#pragma unroll
  for (int off = 32; off; off >>= 1) s += __shfl_xor(s, off);
  __syncthreads();
  if ((t & 63) == 0) red[t >> 6] = s;
  __syncthreads();
  if (t == 0) bc[1] = 1.f / (red[0] + red[1] + red[2] + red[3]);
  __syncthreads();
  const float inv = bc[1];
  p[t] = e0 * inv;
  p[t + 256] = e1 * inv;
  p[t + 512] = e2 * inv;
}

// ------------------------------------------------ O_h = A_h @ V_h  (per head)
__global__ __launch_bounds__(192) void av_kernel(
    const float* __restrict__ att, const float* __restrict__ v,
    float* __restrict__ o) {
  __shared__ float As[64][68];  // [k][q]
  __shared__ float Vs[64][52];  // [k][d]
  const int t = threadIdx.x;
  const int m0 = blockIdx.x * 64;
  const int h = blockIdx.y;
  const int r0 = (t / 12) * 4;
  const int c0 = (t % 12) * 4;
  float acc[4][4] = {};
  for (int k0 = 0; k0 < NT; k0 += 64) {
    __syncthreads();
    for (int idx = t; idx < 1024; idx += 192) {
      int row = idx >> 4, cc = (idx & 15) * 4;
      float4 av = *(const float4*)&att[(h * NT + m0 + row) * NT + k0 + cc];
      As[cc + 0][row] = av.x; As[cc + 1][row] = av.y;
      As[cc + 2][row] = av.z; As[cc + 3][row] = av.w;
    }
    for (int idx = t; idx < 768; idx += 192) {
      int row = idx / 12, dc = (idx % 12) * 4;
      *(float4*)&Vs[row][dc] =
          *(const float4*)&v[(k0 + row) * DT + h * HDT + dc];
    }
    __syncthreads();
#pragma unroll
    for (int kk = 0; kk < 64; kk++) {
      float a4[4], b4[4];
      *(float4*)a4 = *(const float4*)&As[kk][r0];
      *(float4*)b4 = *(const float4*)&Vs[kk][c0];
#pragma unroll
      for (int i = 0; i < 4; i++)
#pragma unroll
        for (int j = 0; j < 4; j++) acc[i][j] += a4[i] * b4[j];
    }
  }
#pragma unroll
  for (int i = 0; i < 4; i++) {
    float4 r;
    r.x = acc[i][0]; r.y = acc[i][1]; r.z = acc[i][2]; r.w = acc[i][3];
    *(float4*)&o[(m0 + r0 + i) * DT + h * HDT + c0] = r;
  }
}

// ---------------------------------------------------- out = (o .* g) @ o_w
__global__ __launch_bounds__(256) void outproj_kernel(
    const float* __restrict__ o, const float* __restrict__ g,
    const float* __restrict__ ow, float* __restrict__ out) {
  __shared__ float As[32][68];
  __shared__ float Bs[32][68];
  const int t = threadIdx.x;
  const int m0 = blockIdx.y * 64;
  const int n0 = blockIdx.x * 64;
  float acc[4][4] = {};
  const int r0 = (t >> 4) * 4;
  const int c0 = (t & 15) * 4;
  const int ar = t >> 3;
  const int ak = (t & 7) * 4;
  const int nc = (t & 7) * 8;
  for (int k0 = 0; k0 < DT; k0 += 32) {
    float4 a0 = *(const float4*)&o[(m0 + ar) * DT + k0 + ak];
    float4 g0 = *(const float4*)&g[(m0 + ar) * DT + k0 + ak];
    float4 a1 = *(const float4*)&o[(m0 + ar + 32) * DT + k0 + ak];
    float4 g1 = *(const float4*)&g[(m0 + ar + 32) * DT + k0 + ak];
    float4 b0 = *(const float4*)&ow[(k0 + ar) * DT + n0 + nc];
    float4 b1 = *(const float4*)&ow[(k0 + ar) * DT + n0 + nc + 4];
    __syncthreads();
    As[ak + 0][ar] = a0.x * g0.x; As[ak + 1][ar] = a0.y * g0.y;
    As[ak + 2][ar] = a0.z * g0.z; As[ak + 3][ar] = a0.w * g0.w;
    As[ak + 0][ar + 32] = a1.x * g1.x; As[ak + 1][ar + 32] = a1.y * g1.y;
    As[ak + 2][ar + 32] = a1.z * g1.z; As[ak + 3][ar + 32] = a1.w * g1.w;
    *(float4*)&Bs[ar][nc] = b0;
    *(float4*)&Bs[ar][nc + 4] = b1;
    __syncthreads();
#pragma unroll
    for (int kk = 0; kk < 32; kk++) {
      float a4[4], b4[4];
      *(float4*)a4 = *(const float4*)&As[kk][r0];
      *(float4*)b4 = *(const float4*)&Bs[kk][c0];
#pragma unroll
      for (int i = 0; i < 4; i++)
#pragma unroll
        for (int j = 0; j < 4; j++) acc[i][j] += a4[i] * b4[j];
    }
  }
#pragma unroll
  for (int i = 0; i < 4; i++) {
    float4 r;
    r.x = acc[i][0]; r.y = acc[i][1]; r.z = acc[i][2]; r.w = acc[i][3];
    *(float4*)&out[(m0 + r0 + i) * DT + n0 + c0] = r;
  }
}

extern "C" void kernel_launch(void* const* d_in, const int* in_sizes, int n_in,
                              void* d_out, int out_size, void* d_ws,
                              size_t ws_size, hipStream_t stream) {
  const float* s = (const float*)d_in[0];
  const float* z = (const float*)d_in[1];
  const float* nsw = (const float*)d_in[2];
  const float* nsb = (const float*)d_in[3];
  const float* qw = (const float*)d_in[4];
  const float* qb = (const float*)d_in[5];
  const float* kw = (const float*)d_in[6];
  const float* vw = (const float*)d_in[7];
  const float* gw = (const float*)d_in[8];
  const float* znw = (const float*)d_in[9];
  const float* znb = (const float*)d_in[10];
  const float* zww = (const float*)d_in[11];
  const float* ow = (const float*)d_in[12];
  float* out = (float*)d_out;
  float* ws = (float*)d_ws;

  float* sn = ws;
  float* qX = ws + (size_t)NN;
  float* kX = ws + (size_t)2 * NN;
  float* vX = ws + (size_t)3 * NN;
  float* gX = ws + (size_t)4 * NN;
  float* oX = ws + (size_t)5 * NN;
  float* att = ws + (size_t)6 * NN;       // 16*NN floats
  float* w1 = ws + (size_t)22 * NN;       // 2048 floats
  float* bh = w1 + 2048;                  // 16 floats

  ln_s_kernel<<<NT, 256, 0, stream>>>(s, nsw, nsb, sn);
  zsetup_kernel<<<1, 256, 0, stream>>>(znw, znb, zww, w1, bh);
  zbias_kernel<<<2304, 256, 0, stream>>>(z, w1, bh, att);
  proj_kernel<<<dim3(12, 12, 4), 256, 0, stream>>>(sn, qw, kw, vw, gw, qb, qX,
                                                   kX, vX, gX);
  scores_kernel<<<dim3(12, 12, 16), 256, 0, stream>>>(qX, kX, att);
  softmax_kernel<<<NT * HT, 256, 0, stream>>>(att);
  av_kernel<<<dim3(12, 16), 192, 0, stream>>>(att, vX, oX);
  outproj_kernel<<<dim3(12, 12), 256, 0, stream>>>(oX, gX, ow, out);
}

// Round 2
// 673.385 us; speedup vs baseline: 1.0257x; 1.0257x over previous
//
#include <hip/hip_runtime.h>
#include <math.h>

constexpr int NT = 768;      // sequence length N
constexpr int DT = 768;      // model dim D
constexpr int HT = 16;       // heads
constexpr int HDT = 48;      // head dim
constexpr int ZDT = 128;     // pair-rep dim
constexpr int NN = NT * NT;  // 589824
constexpr float LN_EPS = 1e-5f;
constexpr float SCALE = 0.14433756729740643f;  // 48^-0.5
constexpr int KP = 72;       // LDS k-stride in bf16 elems (64 + 8 pad, 144B rows)

typedef __attribute__((ext_vector_type(8))) short bfrag;   // 8 bf16 (4 VGPR)
typedef __attribute__((ext_vector_type(4))) float ffrag;   // 4 fp32 acc

#define MFMA16(a, b, c) __builtin_amdgcn_mfma_f32_16x16x32_bf16(a, b, c, 0, 0, 0)

__device__ __forceinline__ short f2b(float f) {
  unsigned u = __builtin_bit_cast(unsigned, f);
  u += 0x7fffu + ((u >> 16) & 1u);   // RNE
  return (short)(u >> 16);
}

// ------------------------------------------- LayerNorm(s) -> bf16 snb [m][k]
__global__ __launch_bounds__(256) void ln_s_kernel(
    const float* __restrict__ s, const float* __restrict__ w,
    const float* __restrict__ b, short* __restrict__ snb) {
  const int row = blockIdx.x;
  const int t = threadIdx.x;
  const float* x = s + row * DT;
  float v0 = x[t], v1 = x[t + 256], v2 = x[t + 512];
  float sum = v0 + v1 + v2;
  float sq = v0 * v0 + v1 * v1 + v2 * v2;
#pragma unroll
  for (int off = 32; off; off >>= 1) {
    sum += __shfl_xor(sum, off);
    sq += __shfl_xor(sq, off);
  }
  __shared__ float ls[4], lq[4], stats[2];
  const int wid = t >> 6;
  if ((t & 63) == 0) { ls[wid] = sum; lq[wid] = sq; }
  __syncthreads();
  if (t == 0) {
    float S = ls[0] + ls[1] + ls[2] + ls[3];
    float Q = lq[0] + lq[1] + lq[2] + lq[3];
    float mu = S * (1.f / DT);
    float var = Q * (1.f / DT) - mu * mu;
    stats[0] = mu;
    stats[1] = rsqrtf(var + LN_EPS);
  }
  __syncthreads();
  const float mu = stats[0], rs = stats[1];
  short* y = snb + row * DT;
  y[t] = f2b((v0 - mu) * rs * w[t] + b[t]);
  y[t + 256] = f2b((v1 - mu) * rs * w[t + 256] + b[t + 256]);
  y[t + 512] = f2b((v2 - mu) * rs * w[t + 512] + b[t + 512]);
}

// ------------------- cast + transpose the 5 weight matrices to bf16 [n][k]
__global__ __launch_bounds__(256) void prep_kernel(
    const float* __restrict__ qw, const float* __restrict__ kw,
    const float* __restrict__ vw, const float* __restrict__ gw,
    const float* __restrict__ ow, short* __restrict__ wt) {
  __shared__ float Ts[64][65];
  const int t = threadIdx.x;
  const int which = blockIdx.z;
  const float* src = which == 0 ? qw : which == 1 ? kw : which == 2 ? vw
                     : which == 3 ? gw : ow;
  short* dst = wt + (size_t)which * NN;
  const int k0 = blockIdx.y * 64;
  const int n0 = blockIdx.x * 64;
  const int r = t >> 4, c = (t & 15) * 4;
#pragma unroll
  for (int i = 0; i < 4; i++) {
    int rr = r + i * 16;
    float4 v = *(const float4*)&src[(k0 + rr) * DT + n0 + c];
    Ts[rr][c + 0] = v.x; Ts[rr][c + 1] = v.y;
    Ts[rr][c + 2] = v.z; Ts[rr][c + 3] = v.w;
  }
  __syncthreads();
#pragma unroll
  for (int i = 0; i < 2; i++) {
    int cid = t + i * 256;          // 512 chunks of 8
    int nr = cid >> 3, kc = cid & 7;
    union { uint4 u; short s[8]; } pk;
#pragma unroll
    for (int j = 0; j < 8; j++) pk.s[j] = f2b(Ts[kc * 8 + j][nr]);
    *(uint4*)&dst[(size_t)(n0 + nr) * DT + k0 + kc * 8] = pk.u;
  }
}

// ---------------------------------- fold z_norm_w into z_w once per call
__global__ __launch_bounds__(256) void zsetup_kernel(
    const float* __restrict__ znw, const float* __restrict__ znb,
    const float* __restrict__ zw, float* __restrict__ w1,
    float* __restrict__ bh) {
  const int t = threadIdx.x;
#pragma unroll
  for (int i = 0; i < 8; i++) {
    int idx = t * 8 + i;
    int c = idx >> 4;
    w1[idx] = znw[c] * zw[idx];
  }
  if (t < HT) {
    float s = 0.f;
    for (int c = 0; c < ZDT; c++) s += znb[c] * zw[c * HT + t];
    bh[t] = s;
  }
}

// ------------------- z LayerNorm + (ZD->H) projection -> att bias [H][N][N]
__global__ __launch_bounds__(256) void zbias_kernel(
    const float* __restrict__ z, const float* __restrict__ w1,
    const float* __restrict__ bh, float* __restrict__ att) {
  __shared__ float xs[8][128];
  const int t = threadIdx.x;
  const int slot = t >> 5;
  const int hq = (t >> 3) & 3;
  const int cg = t & 7;
  const int c0 = cg * 16;
  const int h0 = hq * 4;
  float4 Wr[16];
#pragma unroll
  for (int j = 0; j < 16; j++)
    Wr[j] = *(const float4*)&w1[(c0 + j) * HT + h0];
  const float4 B4 = *(const float4*)&bh[h0];
  const int row0 = blockIdx.x * 256;
  const int lc = (t & 31) * 4;
  for (int it = 0; it < 32; it++) {
    const int rbase = row0 + it * 8;
    float4 xv = *(const float4*)&z[(size_t)(rbase + slot) * ZDT + lc];
    __syncthreads();
    *(float4*)&xs[slot][lc] = xv;
    __syncthreads();
    float x[16];
#pragma unroll
    for (int i = 0; i < 4; i++) {
      float4 v = *(const float4*)&xs[slot][c0 + i * 4];
      x[i * 4 + 0] = v.x; x[i * 4 + 1] = v.y;
      x[i * 4 + 2] = v.z; x[i * 4 + 3] = v.w;
    }
    float sum = 0.f, sq = 0.f;
#pragma unroll
    for (int j = 0; j < 16; j++) { sum += x[j]; sq += x[j] * x[j]; }
#pragma unroll
    for (int m = 1; m <= 4; m <<= 1) {
      sum += __shfl_xor(sum, m);
      sq += __shfl_xor(sq, m);
    }
    const float mu = sum * (1.f / 128.f);
    const float rs = rsqrtf(sq * (1.f / 128.f) - mu * mu + LN_EPS);
    float ax = 0.f, ay = 0.f, az = 0.f, aw = 0.f;
#pragma unroll
    for (int j = 0; j < 16; j++) {
      float xc = x[j] - mu;
      ax += xc * Wr[j].x; ay += xc * Wr[j].y;
      az += xc * Wr[j].z; aw += xc * Wr[j].w;
    }
#pragma unroll
    for (int m = 1; m <= 4; m <<= 1) {
      ax += __shfl_xor(ax, m); ay += __shfl_xor(ay, m);
      az += __shfl_xor(az, m); aw += __shfl_xor(aw, m);
    }
    if (cg == 0) {
      const int rid = rbase + slot;
      att[(size_t)(h0 + 0) * NN + rid] = ax * rs + B4.x;
      att[(size_t)(h0 + 1) * NN + rid] = ay * rs + B4.y;
      att[(size_t)(h0 + 2) * NN + rid] = az * rs + B4.z;
      att[(size_t)(h0 + 3) * NN + rid] = aw * rs + B4.w;
    }
  }
}

// ------------------------------- q/k/v/g projections via bf16 MFMA, 128x128
__global__ __launch_bounds__(256) void proj_kernel(
    const short* __restrict__ snb, const short* __restrict__ wt,
    const float* __restrict__ qbias, short* __restrict__ qb,
    short* __restrict__ kb, short* __restrict__ vT, short* __restrict__ gb) {
  __shared__ short As[128 * KP];
  __shared__ short Bs[128 * KP];
  const int t = threadIdx.x;
  const int which = blockIdx.z;
  const short* W = wt + (size_t)which * NN;
  const int N0 = blockIdx.x * 128;
  const int M0 = blockIdx.y * 128;
  const int w = t >> 6, l = t & 63;
  const int wm = (w >> 1) * 64, wn = (w & 1) * 64;
  const int lane16 = l & 15, quad = l >> 4;
  ffrag acc[4][4] = {};
  const int srow = t >> 3, skc = t & 7;   // staging: 8 rows handled 4x
  for (int k0 = 0; k0 < DT; k0 += 64) {
    uint4 av[4], bv[4];
#pragma unroll
    for (int i = 0; i < 4; i++) {
      int row = srow + i * 32;
      av[i] = *(const uint4*)&snb[(size_t)(M0 + row) * DT + k0 + skc * 8];
      bv[i] = *(const uint4*)&W[(size_t)(N0 + row) * DT + k0 + skc * 8];
    }
    __syncthreads();
#pragma unroll
    for (int i = 0; i < 4; i++) {
      int row = srow + i * 32;
      *(uint4*)&As[row * KP + skc * 8] = av[i];
      *(uint4*)&Bs[row * KP + skc * 8] = bv[i];
    }
    __syncthreads();
#pragma unroll
    for (int ks = 0; ks < 2; ks++) {
      bfrag a[4], b[4];
#pragma unroll
      for (int i = 0; i < 4; i++)
        a[i] = *(const bfrag*)&As[(wm + i * 16 + lane16) * KP + ks * 32 + quad * 8];
#pragma unroll
      for (int j = 0; j < 4; j++)
        b[j] = *(const bfrag*)&Bs[(wn + j * 16 + lane16) * KP + ks * 32 + quad * 8];
#pragma unroll
      for (int i = 0; i < 4; i++)
#pragma unroll
        for (int j = 0; j < 4; j++) acc[i][j] = MFMA16(a[i], b[j], acc[i][j]);
    }
    __syncthreads();
  }
  // epilogue: C/D layout col=lane&15, row=quad*4+reg
#pragma unroll
  for (int i = 0; i < 4; i++) {
#pragma unroll
    for (int j = 0; j < 4; j++) {
      int n = N0 + wn + j * 16 + lane16;
#pragma unroll
      for (int r = 0; r < 4; r++) {
        int m = M0 + wm + i * 16 + quad * 4 + r;
        float v = acc[i][j][r];
        if (which == 0) {
          qb[(size_t)m * DT + n] = f2b(v + qbias[n]);
        } else if (which == 1) {
          kb[(size_t)m * DT + n] = f2b(v);
        } else if (which == 2) {
          vT[(size_t)n * NT + m] = f2b(v);   // transposed for AV B-operand
        } else {
          gb[(size_t)m * DT + n] = f2b(1.f / (1.f + __expf(-v)));
        }
      }
    }
  }
}

// ---------------- scores: att[h][q][k'] = scale*(Q.K'^T) + att  (bf16 MFMA)
__global__ __launch_bounds__(256) void scores_kernel(
    const short* __restrict__ qb, const short* __restrict__ kb,
    float* __restrict__ att) {
  __shared__ short As[128 * KP];
  __shared__ short Bs[128 * KP];
  const int t = threadIdx.x;
  const int h = blockIdx.z;
  const int K0 = blockIdx.x * 128;
  const int Q0 = blockIdx.y * 128;
  const int w = t >> 6, l = t & 63;
  const int wm = (w >> 1) * 64, wn = (w & 1) * 64;
  const int lane16 = l & 15, quad = l >> 4;
  const int srow = t >> 3, skc = t & 7;
  const uint4 zero4 = {0, 0, 0, 0};
#pragma unroll
  for (int i = 0; i < 4; i++) {
    int row = srow + i * 32;
    uint4 qv = zero4, kv = zero4;
    if (skc < 6) {
      qv = *(const uint4*)&qb[(size_t)(Q0 + row) * DT + h * HDT + skc * 8];
      kv = *(const uint4*)&kb[(size_t)(K0 + row) * DT + h * HDT + skc * 8];
    }
    *(uint4*)&As[row * KP + skc * 8] = qv;
    *(uint4*)&Bs[row * KP + skc * 8] = kv;
  }
  __syncthreads();
  ffrag acc[4][4] = {};
#pragma unroll
  for (int ks = 0; ks < 2; ks++) {
    bfrag a[4], b[4];
#pragma unroll
    for (int i = 0; i < 4; i++)
      a[i] = *(const bfrag*)&As[(wm + i * 16 + lane16) * KP + ks * 32 + quad * 8];
#pragma unroll
    for (int j = 0; j < 4; j++)
      b[j] = *(const bfrag*)&Bs[(wn + j * 16 + lane16) * KP + ks * 32 + quad * 8];
#pragma unroll
    for (int i = 0; i < 4; i++)
#pragma unroll
      for (int j = 0; j < 4; j++) acc[i][j] = MFMA16(a[i], b[j], acc[i][j]);
  }
#pragma unroll
  for (int i = 0; i < 4; i++)
#pragma unroll
    for (int j = 0; j < 4; j++) {
      int n = K0 + wn + j * 16 + lane16;
#pragma unroll
      for (int r = 0; r < 4; r++) {
        int m = Q0 + wm + i * 16 + quad * 4 + r;
        size_t idx = ((size_t)h * NT + m) * NT + n;
        att[idx] = acc[i][j][r] * SCALE + att[idx];
      }
    }
}

// ----------------------- softmax over last dim; att fp32 -> probs bf16
__global__ __launch_bounds__(256) void softmax_kernel(
    const float* __restrict__ att, short* __restrict__ probs) {
  const float* p = att + (size_t)blockIdx.x * NT;
  short* q = probs + (size_t)blockIdx.x * NT;
  const int t = threadIdx.x;
  float a = p[t], b = p[t + 256], c = p[t + 512];
  float m = fmaxf(a, fmaxf(b, c));
#pragma unroll
  for (int off = 32; off; off >>= 1) m = fmaxf(m, __shfl_xor(m, off));
  __shared__ float red[4];
  __shared__ float bc[2];
  if ((t & 63) == 0) red[t >> 6] = m;
  __syncthreads();
  if (t == 0) bc[0] = fmaxf(fmaxf(red[0], red[1]), fmaxf(red[2], red[3]));
  __syncthreads();
  const float M = bc[0];
  float e0 = __expf(a - M), e1 = __expf(b - M), e2 = __expf(c - M);
  float s = e0 + e1 + e2;
#pragma unroll
  for (int off = 32; off; off >>= 1) s += __shfl_xor(s, off);
  __syncthreads();
  if ((t & 63) == 0) red[t >> 6] = s;
  __syncthreads();
  if (t == 0) bc[1] = 1.f / (red[0] + red[1] + red[2] + red[3]);
  __syncthreads();
  const float inv = bc[1];
  q[t] = f2b(e0 * inv);
  q[t + 256] = f2b(e1 * inv);
  q[t + 512] = f2b(e2 * inv);
}

// ----------------- O_h = P_h @ V_h via bf16 MFMA. tile 128(q) x 48(d)
__global__ __launch_bounds__(256) void av_kernel(
    const short* __restrict__ probs, const short* __restrict__ vT,
    float* __restrict__ oX) {
  __shared__ short Ps[128 * KP];
  __shared__ short Vs[48 * KP];
  const int t = threadIdx.x;
  const int h = blockIdx.y;
  const int Q0 = blockIdx.x * 128;
  const int w = t >> 6, l = t & 63;
  const int lane16 = l & 15, quad = l >> 4;
  const int srow = t >> 3, skc = t & 7;
  ffrag acc[2][3] = {};
  const short* ph = probs + (size_t)h * NN;
  const short* vh = vT + (size_t)h * HDT * NT;
  for (int k0 = 0; k0 < NT; k0 += 64) {
    uint4 pv[4];
#pragma unroll
    for (int i = 0; i < 4; i++)
      pv[i] = *(const uint4*)&ph[(size_t)(Q0 + srow + i * 32) * NT + k0 + skc * 8];
    uint4 vv[2];
#pragma unroll
    for (int i = 0; i < 2; i++) {
      int cid = t + i * 256;
      if (cid < 384)
        vv[i] = *(const uint4*)&vh[(size_t)(cid >> 3) * NT + k0 + (cid & 7) * 8];
    }
    __syncthreads();
#pragma unroll
    for (int i = 0; i < 4; i++)
      *(uint4*)&Ps[(srow + i * 32) * KP + skc * 8] = pv[i];
#pragma unroll
    for (int i = 0; i < 2; i++) {
      int cid = t + i * 256;
      if (cid < 384) *(uint4*)&Vs[(cid >> 3) * KP + (cid & 7) * 8] = vv[i];
    }
    __syncthreads();
#pragma unroll
    for (int ks = 0; ks < 2; ks++) {
      bfrag a[2], b[3];
#pragma unroll
      for (int i = 0; i < 2; i++)
        a[i] = *(const bfrag*)&Ps[(w * 32 + i * 16 + lane16) * KP + ks * 32 + quad * 8];
#pragma unroll
      for (int j = 0; j < 3; j++)
        b[j] = *(const bfrag*)&Vs[(j * 16 + lane16) * KP + ks * 32 + quad * 8];
#pragma unroll
      for (int i = 0; i < 2; i++)
#pragma unroll
        for (int j = 0; j < 3; j++) acc[i][j] = MFMA16(a[i], b[j], acc[i][j]);
    }
    __syncthreads();
  }
#pragma unroll
  for (int i = 0; i < 2; i++)
#pragma unroll
    for (int j = 0; j < 3; j++) {
      int d = h * HDT + j * 16 + lane16;
#pragma unroll
      for (int r = 0; r < 4; r++) {
        int m = Q0 + w * 32 + i * 16 + quad * 4 + r;
        oX[(size_t)m * DT + d] = acc[i][j][r];
      }
    }
}

// ---------------------------- out = (o .* g) @ o_w via bf16 MFMA, 128x128
__global__ __launch_bounds__(256) void outproj_kernel(
    const float* __restrict__ oX, const short* __restrict__ gb,
    const short* __restrict__ owt, float* __restrict__ out) {
  __shared__ short As[128 * KP];
  __shared__ short Bs[128 * KP];
  const int t = threadIdx.x;
  const int N0 = blockIdx.x * 128;
  const int M0 = blockIdx.y * 128;
  const int w = t >> 6, l = t & 63;
  const int wm = (w >> 1) * 64, wn = (w & 1) * 64;
  const int lane16 = l & 15, quad = l >> 4;
  ffrag acc[4][4] = {};
  const int srow = t >> 3, skc = t & 7;
  for (int k0 = 0; k0 < DT; k0 += 64) {
#pragma unroll
    for (int i = 0; i < 4; i++) {
      int row = srow + i * 32;
      float4 o0 = *(const float4*)&oX[(size_t)(M0 + row) * DT + k0 + skc * 8];
      float4 o1 = *(const float4*)&oX[(size_t)(M0 + row) * DT + k0 + skc * 8 + 4];
      union { uint4 u; short s[8]; } gv;
      gv.u = *(const uint4*)&gb[(size_t)(M0 + row) * DT + k0 + skc * 8];
      union { uint4 u; short s[8]; } pk;
      float go[8] = {o0.x, o0.y, o0.z, o0.w, o1.x, o1.y, o1.z, o1.w};
#pragma unroll
      for (int jj = 0; jj < 8; jj++) {
        float g = __builtin_bit_cast(float, (unsigned)(unsigned short)gv.s[jj] << 16);
        pk.s[jj] = f2b(go[jj] * g);
      }
      uint4 bv = *(const uint4*)&owt[(size_t)(N0 + row) * DT + k0 + skc * 8];
      __syncthreads();
      *(uint4*)&As[row * KP + skc * 8] = pk.u;
      *(uint4*)&Bs[row * KP + skc * 8] = bv;
      __syncthreads();
      if (i < 3) __syncthreads();  // keep loads/stores of the 4 sub-stages ordered
    }
    // NOTE: the i-loop above stages all 128 rows; barriers inside keep it safe.
#pragma unroll
    for (int ks = 0; ks < 2; ks++) {
      bfrag a[4], b[4];
#pragma unroll
      for (int i = 0; i < 4; i++)
        a[i] = *(const bfrag*)&As[(wm + i * 16 + lane16) * KP + ks * 32 + quad * 8];
#pragma unroll
      for (int j = 0; j < 4; j++)
        b[j] = *(const bfrag*)&Bs[(wn + j * 16 + lane16) * KP + ks * 32 + quad * 8];
#pragma unroll
      for (int i = 0; i < 4; i++)
#pragma unroll
        for (int j = 0; j < 4; j++) acc[i][j] = MFMA16(a[i], b[j], acc[i][j]);
    }
    __syncthreads();
  }
#pragma unroll
  for (int i = 0; i < 4; i++)
#pragma unroll
    for (int j = 0; j < 4; j++) {
      int n = N0 + wn + j * 16 + lane16;
#pragma unroll
      for (int r = 0; r < 4; r++) {
        int m = M0 + wm + i * 16 + quad * 4 + r;
        out[(size_t)m * DT + n] = acc[i][j][r];
      }
    }
}

extern "C" void kernel_launch(void* const* d_in, const int* in_sizes, int n_in,
                              void* d_out, int out_size, void* d_ws,
                              size_t ws_size, hipStream_t stream) {
  const float* s = (const float*)d_in[0];
  const float* z = (const float*)d_in[1];
  const float* nsw = (const float*)d_in[2];
  const float* nsb = (const float*)d_in[3];
  const float* qw = (const float*)d_in[4];
  const float* qbias = (const float*)d_in[5];
  const float* kw = (const float*)d_in[6];
  const float* vw = (const float*)d_in[7];
  const float* gw = (const float*)d_in[8];
  const float* znw = (const float*)d_in[9];
  const float* znb = (const float*)d_in[10];
  const float* zww = (const float*)d_in[11];
  const float* ow = (const float*)d_in[12];
  float* out = (float*)d_out;
  char* W = (char*)d_ws;

  float* att = (float*)W;                           // 37,748,736 B
  short* probs = (short*)(W + 37748736);            // 18,874,368 B
  short* snb = (short*)(W + 56623104);              // 1,179,648 B
  short* qb = (short*)(W + 57802752);
  short* kb = (short*)(W + 58982400);
  short* gb = (short*)(W + 60162048);
  short* vT = (short*)(W + 61341696);
  short* wt = (short*)(W + 62521344);               // 5 x 1,179,648 B
  float* oX = (float*)(W + 68419584);               // 2,359,296 B
  float* w1 = (float*)(W + 70778880);               // 8 KB
  float* bh = (float*)(W + 70787072);

  ln_s_kernel<<<NT, 256, 0, stream>>>(s, nsw, nsb, snb);
  zsetup_kernel<<<1, 256, 0, stream>>>(znw, znb, zww, w1, bh);
  prep_kernel<<<dim3(12, 12, 5), 256, 0, stream>>>(qw, kw, vw, gw, ow, wt);
  zbias_kernel<<<2304, 256, 0, stream>>>(z, w1, bh, att);
  proj_kernel<<<dim3(6, 6, 4), 256, 0, stream>>>(snb, wt, qbias, qb, kb, vT, gb);
  scores_kernel<<<dim3(6, 6, 16), 256, 0, stream>>>(qb, kb, att);
  softmax_kernel<<<NT * HT, 256, 0, stream>>>(att, probs);
  av_kernel<<<dim3(6, 16), 256, 0, stream>>>(probs, vT, oX);
  outproj_kernel<<<dim3(6, 6), 256, 0, stream>>>(oX, gb, wt + 4 * (size_t)NN,
                                                 out);
}

// Round 4
// 602.633 us; speedup vs baseline: 1.1461x; 1.1174x over previous
//
#include <hip/hip_runtime.h>
#include <math.h>

constexpr int NT = 768;      // sequence length N
constexpr int DT = 768;      // model dim D
constexpr int HT = 16;       // heads
constexpr int HDT = 48;      // head dim
constexpr int ZDT = 128;     // pair-rep dim
constexpr int NN = NT * NT;  // 589824
constexpr float LN_EPS = 1e-5f;
constexpr float SCALE = 0.14433756729740643f;  // 48^-0.5
constexpr int KP = 72;       // LDS k-stride in bf16 elems (64 + 8 pad)

typedef __attribute__((ext_vector_type(8))) short bfrag;   // 8 bf16 (4 VGPR)
typedef __attribute__((ext_vector_type(4))) float ffrag;   // 4 fp32 acc

#define MFMA16(a, b, c) __builtin_amdgcn_mfma_f32_16x16x32_bf16(a, b, c, 0, 0, 0)

__device__ __forceinline__ short f2b(float f) {
  unsigned u = __builtin_bit_cast(unsigned, f);
  u += 0x7fffu + ((u >> 16) & 1u);   // RNE
  return (short)(u >> 16);
}
__device__ __forceinline__ float b2f(short s) {
  return __builtin_bit_cast(float, (unsigned)(unsigned short)s << 16);
}

// ------------------------------------------- LayerNorm(s) -> bf16 snb [m][k]
__global__ __launch_bounds__(256) void ln_s_kernel(
    const float* __restrict__ s, const float* __restrict__ w,
    const float* __restrict__ b, short* __restrict__ snb) {
  const int row = blockIdx.x;
  const int t = threadIdx.x;
  const float* x = s + row * DT;
  float v0 = x[t], v1 = x[t + 256], v2 = x[t + 512];
  float sum = v0 + v1 + v2;
  float sq = v0 * v0 + v1 * v1 + v2 * v2;
#pragma unroll
  for (int off = 32; off; off >>= 1) {
    sum += __shfl_xor(sum, off);
    sq += __shfl_xor(sq, off);
  }
  __shared__ float ls[4], lq[4], stats[2];
  const int wid = t >> 6;
  if ((t & 63) == 0) { ls[wid] = sum; lq[wid] = sq; }
  __syncthreads();
  if (t == 0) {
    float S = ls[0] + ls[1] + ls[2] + ls[3];
    float Q = lq[0] + lq[1] + lq[2] + lq[3];
    float mu = S * (1.f / DT);
    float var = Q * (1.f / DT) - mu * mu;
    stats[0] = mu;
    stats[1] = rsqrtf(var + LN_EPS);
  }
  __syncthreads();
  const float mu = stats[0], rs = stats[1];
  short* y = snb + row * DT;
  y[t] = f2b((v0 - mu) * rs * w[t] + b[t]);
  y[t + 256] = f2b((v1 - mu) * rs * w[t + 256] + b[t + 256]);
  y[t + 512] = f2b((v2 - mu) * rs * w[t + 512] + b[t + 512]);
}

// ------------------- cast + transpose the 5 weight matrices to bf16 [n][k]
__global__ __launch_bounds__(256) void prep_kernel(
    const float* __restrict__ qw, const float* __restrict__ kw,
    const float* __restrict__ vw, const float* __restrict__ gw,
    const float* __restrict__ ow, short* __restrict__ wt) {
  __shared__ float Ts[64][65];
  const int t = threadIdx.x;
  const int which = blockIdx.z;
  const float* src = which == 0 ? qw : which == 1 ? kw : which == 2 ? vw
                     : which == 3 ? gw : ow;
  short* dst = wt + (size_t)which * NN;
  const int k0 = blockIdx.y * 64;
  const int n0 = blockIdx.x * 64;
  const int r = t >> 4, c = (t & 15) * 4;
#pragma unroll
  for (int i = 0; i < 4; i++) {
    int rr = r + i * 16;
    float4 v = *(const float4*)&src[(size_t)(k0 + rr) * DT + n0 + c];
    Ts[rr][c + 0] = v.x; Ts[rr][c + 1] = v.y;
    Ts[rr][c + 2] = v.z; Ts[rr][c + 3] = v.w;
  }
  __syncthreads();
#pragma unroll
  for (int i = 0; i < 2; i++) {
    int cid = t + i * 256;          // 512 chunks of 8
    int nr = cid >> 3, kc = cid & 7;
    union { uint4 u; short s2[8]; } pk;
#pragma unroll
    for (int j = 0; j < 8; j++) pk.s2[j] = f2b(Ts[kc * 8 + j][nr]);
    *(uint4*)&dst[(size_t)(n0 + nr) * DT + k0 + kc * 8] = pk.u;
  }
}

// ---------------------------------- fold z_norm_w into z_w once per call
__global__ __launch_bounds__(256) void zsetup_kernel(
    const float* __restrict__ znw, const float* __restrict__ znb,
    const float* __restrict__ zw, float* __restrict__ w1,
    float* __restrict__ bh) {
  const int t = threadIdx.x;
#pragma unroll
  for (int i = 0; i < 8; i++) {
    int idx = t * 8 + i;
    int c = idx >> 4;
    w1[idx] = znw[c] * zw[idx];
  }
  if (t < HT) {
    float s = 0.f;
    for (int c = 0; c < ZDT; c++) s += znb[c] * zw[c * HT + t];
    bh[t] = s;
  }
}

// --------- z LayerNorm + (ZD->H) projection -> bf16 bias [H][N*N]
__global__ __launch_bounds__(256) void zbias_kernel(
    const float* __restrict__ z, const float* __restrict__ w1,
    const float* __restrict__ bh, short* __restrict__ biasb) {
  const int t = threadIdx.x;
  const int slot = t >> 5;
  const int hq = (t >> 3) & 3;
  const int cg = t & 7;
  const int c0 = cg * 16;
  const int h0 = hq * 4;
  float4 Wr[16];
#pragma unroll
  for (int j = 0; j < 16; j++)
    Wr[j] = *(const float4*)&w1[(c0 + j) * HT + h0];
  const float4 B4 = *(const float4*)&bh[h0];
  const int row0 = blockIdx.x * 256;
  for (int it = 0; it < 32; it++) {
    const int rid = row0 + it * 8 + slot;
    const float* zp = &z[(size_t)rid * ZDT + c0];
    float x[16];
    *(float4*)&x[0] = *(const float4*)&zp[0];
    *(float4*)&x[4] = *(const float4*)&zp[4];
    *(float4*)&x[8] = *(const float4*)&zp[8];
    *(float4*)&x[12] = *(const float4*)&zp[12];
    float sum = 0.f, sq = 0.f;
#pragma unroll
    for (int j = 0; j < 16; j++) { sum += x[j]; sq += x[j] * x[j]; }
#pragma unroll
    for (int m = 1; m <= 4; m <<= 1) {
      sum += __shfl_xor(sum, m);
      sq += __shfl_xor(sq, m);
    }
    const float mu = sum * (1.f / 128.f);
    const float rs = rsqrtf(sq * (1.f / 128.f) - mu * mu + LN_EPS);
    float ax = 0.f, ay = 0.f, az = 0.f, aw = 0.f;
#pragma unroll
    for (int j = 0; j < 16; j++) {
      float xc = x[j] - mu;
      ax += xc * Wr[j].x; ay += xc * Wr[j].y;
      az += xc * Wr[j].z; aw += xc * Wr[j].w;
    }
#pragma unroll
    for (int m = 1; m <= 4; m <<= 1) {
      ax += __shfl_xor(ax, m); ay += __shfl_xor(ay, m);
      az += __shfl_xor(az, m); aw += __shfl_xor(aw, m);
    }
    if (cg == 0) {
      biasb[(size_t)(h0 + 0) * NN + rid] = f2b(ax * rs + B4.x);
      biasb[(size_t)(h0 + 1) * NN + rid] = f2b(ay * rs + B4.y);
      biasb[(size_t)(h0 + 2) * NN + rid] = f2b(az * rs + B4.z);
      biasb[(size_t)(h0 + 3) * NN + rid] = f2b(aw * rs + B4.w);
    }
  }
}

// ------------------------------- q/k/v/g projections via bf16 MFMA, 128x128
__global__ __launch_bounds__(256) void proj_kernel(
    const short* __restrict__ snb, const short* __restrict__ wt,
    const float* __restrict__ qbias, short* __restrict__ qb,
    short* __restrict__ kb, short* __restrict__ vT, short* __restrict__ gb) {
  __shared__ short As[128 * KP];
  __shared__ short Bs[128 * KP];
  const int t = threadIdx.x;
  const int which = blockIdx.z;
  const short* W = wt + (size_t)which * NN;
  const int N0 = blockIdx.x * 128;
  const int M0 = blockIdx.y * 128;
  const int w = t >> 6, l = t & 63;
  const int wm = (w >> 1) * 64, wn = (w & 1) * 64;
  const int lane16 = l & 15, quad = l >> 4;
  ffrag acc[4][4] = {};
  const int srow = t >> 3, skc = t & 7;
  for (int k0 = 0; k0 < DT; k0 += 64) {
    uint4 av[4], bv[4];
#pragma unroll
    for (int i = 0; i < 4; i++) {
      int row = srow + i * 32;
      av[i] = *(const uint4*)&snb[(size_t)(M0 + row) * DT + k0 + skc * 8];
      bv[i] = *(const uint4*)&W[(size_t)(N0 + row) * DT + k0 + skc * 8];
    }
    __syncthreads();
#pragma unroll
    for (int i = 0; i < 4; i++) {
      int row = srow + i * 32;
      *(uint4*)&As[row * KP + skc * 8] = av[i];
      *(uint4*)&Bs[row * KP + skc * 8] = bv[i];
    }
    __syncthreads();
#pragma unroll
    for (int ks = 0; ks < 2; ks++) {
      bfrag a[4], b[4];
#pragma unroll
      for (int i = 0; i < 4; i++)
        a[i] = *(const bfrag*)&As[(wm + i * 16 + lane16) * KP + ks * 32 + quad * 8];
#pragma unroll
      for (int j = 0; j < 4; j++)
        b[j] = *(const bfrag*)&Bs[(wn + j * 16 + lane16) * KP + ks * 32 + quad * 8];
#pragma unroll
      for (int i = 0; i < 4; i++)
#pragma unroll
        for (int j = 0; j < 4; j++) acc[i][j] = MFMA16(a[i], b[j], acc[i][j]);
    }
    __syncthreads();
  }
#pragma unroll
  for (int i = 0; i < 4; i++) {
#pragma unroll
    for (int j = 0; j < 4; j++) {
      int n = N0 + wn + j * 16 + lane16;
#pragma unroll
      for (int r = 0; r < 4; r++) {
        int m = M0 + wm + i * 16 + quad * 4 + r;
        float v = acc[i][j][r];
        if (which == 0) {
          qb[(size_t)m * DT + n] = f2b(v + qbias[n]);
        } else if (which == 1) {
          kb[(size_t)m * DT + n] = f2b(v);
        } else if (which == 2) {
          vT[(size_t)n * NT + m] = f2b(v);   // [h*48+d][seq] for AV B-operand
        } else {
          gb[(size_t)m * DT + n] = f2b(1.f / (1.f + __expf(-v)));
        }
      }
    }
  }
}

// ------- fused attention: S=QK^T*scale+bias, online softmax, O=PV
// grid (12 q-tiles of 64, 16 heads); 4 waves, wave w owns q-rows w*16..+16
__global__ __launch_bounds__(256) void attn_kernel(
    const short* __restrict__ qb, const short* __restrict__ kb,
    const short* __restrict__ vT, const short* __restrict__ biasb,
    float* __restrict__ oX) {
  __shared__ short Ks[128 * 48];       // [kpos][d]
  __shared__ short Vs[48 * 136];       // [d][kpos+8 pad]
  __shared__ short Ps[4][16 * 136];    // per-wave private P slice
  const int t = threadIdx.x;
  const int h = blockIdx.y;
  const int q0 = blockIdx.x * 64;
  const int w = t >> 6, l = t & 63;
  const int lane16 = l & 15, quad = l >> 4;
  // Q A-frags (A[m=lane16][k=quad*8+j]) live in registers for the whole kernel
  const int qrow = q0 + w * 16 + lane16;
  bfrag a_q0 = *(const bfrag*)&qb[(size_t)qrow * DT + h * HDT + quad * 8];
  bfrag a_q1 = {0, 0, 0, 0, 0, 0, 0, 0};   // k 48..63 zero-padded
  if (quad < 2)
    a_q1 = *(const bfrag*)&qb[(size_t)qrow * DT + h * HDT + 32 + quad * 8];
  // FIX(r3->r4): quad>=2 lanes must NOT read past the 48-short K row (row 127
  // overran the Ks allocation -> uninitialized LDS -> 0*NaN=NaN). Their A-frag
  // is zero, so clamp them to a safe in-row address instead.
  const int koff1 = (quad < 2) ? (32 + quad * 8) : 0;
  ffrag acc_o[3] = {};
  float m_run[4] = {-1e30f, -1e30f, -1e30f, -1e30f};
  float l_run[4] = {};
  const size_t bias_base =
      (size_t)h * NN + (size_t)(q0 + w * 16 + quad * 4) * NT + lane16;
  for (int kt = 0; kt < 6; kt++) {
    const int k0 = kt * 128;
    uint4 kv[3], vv[3];
#pragma unroll
    for (int i = 0; i < 3; i++) {
      int cid = t + i * 256;
      int kr = cid / 6, kc = cid % 6;
      kv[i] = *(const uint4*)&kb[(size_t)(k0 + kr) * DT + h * HDT + kc * 8];
      int vr = cid >> 4, vc = cid & 15;
      vv[i] = *(const uint4*)&vT[((size_t)h * HDT + vr) * NT + k0 + vc * 8];
    }
    short bias_s[8][4];
#pragma unroll
    for (int j = 0; j < 8; j++)
#pragma unroll
      for (int r = 0; r < 4; r++)
        bias_s[j][r] = biasb[bias_base + (size_t)r * NT + k0 + j * 16];
    __syncthreads();
#pragma unroll
    for (int i = 0; i < 3; i++) {
      int cid = t + i * 256;
      int kr = cid / 6, kc = cid % 6;
      *(uint4*)&Ks[kr * 48 + kc * 8] = kv[i];
      int vr = cid >> 4, vc = cid & 15;
      *(uint4*)&Vs[vr * 136 + vc * 8] = vv[i];
    }
    __syncthreads();
    // S = Q K^T   (8 n-tiles x 2 k-steps)
    ffrag sc[8];
#pragma unroll
    for (int j = 0; j < 8; j++) {
      ffrag zf = {0.f, 0.f, 0.f, 0.f};
      bfrag b0 = *(const bfrag*)&Ks[(j * 16 + lane16) * 48 + quad * 8];
      bfrag b1 = *(const bfrag*)&Ks[(j * 16 + lane16) * 48 + koff1];
      zf = MFMA16(a_q0, b0, zf);
      sc[j] = MFMA16(a_q1, b1, zf);
    }
    // logits + online softmax (C layout: col=lane16, row=quad*4+r)
    float li[8][4];
#pragma unroll
    for (int j = 0; j < 8; j++)
#pragma unroll
      for (int r = 0; r < 4; r++)
        li[j][r] = sc[j][r] * SCALE + b2f(bias_s[j][r]);
    float alpha[4];
#pragma unroll
    for (int r = 0; r < 4; r++) {
      float m = li[0][r];
#pragma unroll
      for (int j = 1; j < 8; j++) m = fmaxf(m, li[j][r]);
#pragma unroll
      for (int k = 1; k <= 8; k <<= 1) m = fmaxf(m, __shfl_xor(m, k));
      float mn = fmaxf(m_run[r], m);
      alpha[r] = __expf(m_run[r] - mn);
      m_run[r] = mn;
    }
#pragma unroll
    for (int j = 0; j < 8; j++)
#pragma unroll
      for (int r = 0; r < 4; r++) li[j][r] = __expf(li[j][r] - m_run[r]);
#pragma unroll
    for (int r = 0; r < 4; r++) {
      float ssum = li[0][r];
#pragma unroll
      for (int j = 1; j < 8; j++) ssum += li[j][r];
#pragma unroll
      for (int k = 1; k <= 8; k <<= 1) ssum += __shfl_xor(ssum, k);
      l_run[r] = l_run[r] * alpha[r] + ssum;
    }
#pragma unroll
    for (int dt = 0; dt < 3; dt++)
#pragma unroll
      for (int r = 0; r < 4; r++) acc_o[dt][r] *= alpha[r];
    // P -> per-wave LDS slice (C layout -> A layout); same-wave RAW is safe:
    // LDS ops from one wave execute in order (DS pipe FIFO per wave)
#pragma unroll
    for (int j = 0; j < 8; j++)
#pragma unroll
      for (int r = 0; r < 4; r++)
        Ps[w][(quad * 4 + r) * 136 + j * 16 + lane16] = f2b(li[j][r]);
    // O += P V   (3 d-tiles x 4 k-steps)
#pragma unroll
    for (int ks = 0; ks < 4; ks++) {
      bfrag ap = *(const bfrag*)&Ps[w][lane16 * 136 + ks * 32 + quad * 8];
#pragma unroll
      for (int dt = 0; dt < 3; dt++) {
        bfrag bv = *(const bfrag*)&Vs[(dt * 16 + lane16) * 136 + ks * 32 + quad * 8];
        acc_o[dt] = MFMA16(ap, bv, acc_o[dt]);
      }
    }
  }
  float inv[4];
#pragma unroll
  for (int r = 0; r < 4; r++) inv[r] = 1.f / l_run[r];
#pragma unroll
  for (int dt = 0; dt < 3; dt++)
#pragma unroll
    for (int r = 0; r < 4; r++)
      oX[(size_t)(q0 + w * 16 + quad * 4 + r) * DT + h * HDT + dt * 16 + lane16] =
          acc_o[dt][r] * inv[r];
}

// ---------------------------- out = (o .* g) @ o_w via bf16 MFMA, 128x128
__global__ __launch_bounds__(256) void outproj_kernel(
    const float* __restrict__ oX, const short* __restrict__ gb,
    const short* __restrict__ owt, float* __restrict__ out) {
  __shared__ short As[128 * KP];
  __shared__ short Bs[128 * KP];
  const int t = threadIdx.x;
  const int N0 = blockIdx.x * 128;
  const int M0 = blockIdx.y * 128;
  const int w = t >> 6, l = t & 63;
  const int wm = (w >> 1) * 64, wn = (w & 1) * 64;
  const int lane16 = l & 15, quad = l >> 4;
  ffrag acc[4][4] = {};
  const int srow = t >> 3, skc = t & 7;
  for (int k0 = 0; k0 < DT; k0 += 64) {
    uint4 apk[4], bvv[4];
#pragma unroll
    for (int i = 0; i < 4; i++) {
      int row = srow + i * 32;
      float4 o0 = *(const float4*)&oX[(size_t)(M0 + row) * DT + k0 + skc * 8];
      float4 o1 = *(const float4*)&oX[(size_t)(M0 + row) * DT + k0 + skc * 8 + 4];
      union { uint4 u; short s2[8]; } gv;
      gv.u = *(const uint4*)&gb[(size_t)(M0 + row) * DT + k0 + skc * 8];
      union { uint4 u; short s2[8]; } pk;
      float go[8] = {o0.x, o0.y, o0.z, o0.w, o1.x, o1.y, o1.z, o1.w};
#pragma unroll
      for (int jj = 0; jj < 8; jj++) pk.s2[jj] = f2b(go[jj] * b2f(gv.s2[jj]));
      apk[i] = pk.u;
      bvv[i] = *(const uint4*)&owt[(size_t)(N0 + row) * DT + k0 + skc * 8];
    }
    __syncthreads();
#pragma unroll
    for (int i = 0; i < 4; i++) {
      int row = srow + i * 32;
      *(uint4*)&As[row * KP + skc * 8] = apk[i];
      *(uint4*)&Bs[row * KP + skc * 8] = bvv[i];
    }
    __syncthreads();
#pragma unroll
    for (int ks = 0; ks < 2; ks++) {
      bfrag a[4], b[4];
#pragma unroll
      for (int i = 0; i < 4; i++)
        a[i] = *(const bfrag*)&As[(wm + i * 16 + lane16) * KP + ks * 32 + quad * 8];
#pragma unroll
      for (int j = 0; j < 4; j++)
        b[j] = *(const bfrag*)&Bs[(wn + j * 16 + lane16) * KP + ks * 32 + quad * 8];
#pragma unroll
      for (int i = 0; i < 4; i++)
#pragma unroll
        for (int j = 0; j < 4; j++) acc[i][j] = MFMA16(a[i], b[j], acc[i][j]);
    }
    __syncthreads();
  }
#pragma unroll
  for (int i = 0; i < 4; i++)
#pragma unroll
    for (int j = 0; j < 4; j++) {
      int n = N0 + wn + j * 16 + lane16;
#pragma unroll
      for (int r = 0; r < 4; r++) {
        int m = M0 + wm + i * 16 + quad * 4 + r;
        out[(size_t)m * DT + n] = acc[i][j][r];
      }
    }
}

extern "C" void kernel_launch(void* const* d_in, const int* in_sizes, int n_in,
                              void* d_out, int out_size, void* d_ws,
                              size_t ws_size, hipStream_t stream) {
  const float* s = (const float*)d_in[0];
  const float* z = (const float*)d_in[1];
  const float* nsw = (const float*)d_in[2];
  const float* nsb = (const float*)d_in[3];
  const float* qw = (const float*)d_in[4];
  const float* qbias = (const float*)d_in[5];
  const float* kw = (const float*)d_in[6];
  const float* vw = (const float*)d_in[7];
  const float* gw = (const float*)d_in[8];
  const float* znw = (const float*)d_in[9];
  const float* znb = (const float*)d_in[10];
  const float* zww = (const float*)d_in[11];
  const float* ow = (const float*)d_in[12];
  float* out = (float*)d_out;
  char* W = (char*)d_ws;

  short* biasb = (short*)W;                        // 18,874,368 B
  short* snb = (short*)(W + 18874368);             // 1,179,648 B
  short* qb = (short*)(W + 20054016);
  short* kb = (short*)(W + 21233664);
  short* gb = (short*)(W + 22413312);
  short* vT = (short*)(W + 23592960);
  short* wt = (short*)(W + 24772608);              // 5 x 1,179,648 B
  float* oX = (float*)(W + 30670848);              // 2,359,296 B
  float* w1 = (float*)(W + 33030144);              // 8 KB
  float* bh = (float*)(W + 33038336);

  ln_s_kernel<<<NT, 256, 0, stream>>>(s, nsw, nsb, snb);
  zsetup_kernel<<<1, 256, 0, stream>>>(znw, znb, zww, w1, bh);
  prep_kernel<<<dim3(12, 12, 5), 256, 0, stream>>>(qw, kw, vw, gw, ow, wt);
  zbias_kernel<<<2304, 256, 0, stream>>>(z, w1, bh, biasb);
  proj_kernel<<<dim3(6, 6, 4), 256, 0, stream>>>(snb, wt, qbias, qb, kb, vT, gb);
  attn_kernel<<<dim3(12, 16), 256, 0, stream>>>(qb, kb, vT, biasb, oX);
  outproj_kernel<<<dim3(6, 6), 256, 0, stream>>>(oX, gb, wt + 4 * (size_t)NN,
                                                 out);
}